// Round 26
// baseline (398.157 us; speedup 1.0000x reference)
//
#include <hip/hip_runtime.h>
#include <hip/hip_fp16.h>
#include <type_traits>

// ---------------------------------------------------------------------------
// GCN 2-layer. N=50000, E=800000, F: 128 -> 128 -> 64.
// Settled floors (measured):
//   - agg: per-XCD L2 duplication, FETCH ~= 7.3x gathered-table bytes @
//     ~3.3TB/s; fp16 z-tables halve it (R16).
//   - fill scatter: WRITE ~= E x 64B when sectors are dirtied by multiple
//     XCDs (partial-copy writebacks); ~50-73us across R18/R25 variants.
// R25: padded CSR (RCAP=96) killed count+scan kernels: 209.8 -> 190.6us.
// R26: XCD-OWNED fill: each XCD streams the full edge list (8x6.4MB reads)
//   but scatters only its 6250-node dst range -> every csr/cursor sector
//   dirtied by exactly ONE L2 -> writeback ~= touched bytes (~6MB).
//   Distribution: block-level chunk tickets (1 atomic / 1024 edges; R21's
//   failure was per-wave tickets) + steal-after-own-queue (correct under
//   any block->XCD placement; locality-only heuristic).
// ---------------------------------------------------------------------------

#define N_NODES 50000
#define N_EDGES 800000
#define RCAP    96        // per-node capacity; max deg ~36 for fixed input
#define NB      8
#define BRANGE  6250      // nodes per XCD range (8*6250 = 50000)
#define FCH     1024      // edges per ticket chunk

// workspace layout (bytes)
static constexpr size_t OFF_CUR  = 0;         // int[50000] cursor (= deg after fill)
static constexpr size_t OFF_QCUR = 200192;    // int[8] chunk tickets
static constexpr size_t OFF_DINV = 200448;    // float[50000]
static constexpr size_t OFF_SRC  = 400640;    // int[50000*96] = 19.2MB padded CSR
static constexpr size_t OFF_Z    = 19600640;  // __half[50000*128] z1 (reused z2)
static constexpr size_t OFF_OUT1 = 32400640;  // __half[50000*128]
// total ~45.2 MB  (memset zeroes [0, OFF_DINV): cursor + qcur)

// ---------------------------------------------------------------------------
// XCD-owned padded-CSR fill. Queue q covers ALL edges; its workers scatter
// only dsts in [q*BRANGE, (q+1)*BRANGE). Blocks serve their own XCD's queue
// first (XCC_ID), then steal. Chunk ticket = one atomic per 1024 edges.
// ---------------------------------------------------------------------------
__global__ __launch_bounds__(256) void fill_xcd_k(const int* __restrict__ ei,
                                                  int* __restrict__ cursor,
                                                  int* __restrict__ csr_src,
                                                  int* __restrict__ qcur) {
    constexpr int NCHUNK = (N_EDGES + FCH - 1) / FCH;  // 782
    __shared__ int sm_chunk;

    int xcd;
    asm volatile("s_getreg_b32 %0, hwreg(HW_REG_XCC_ID)" : "=s"(xcd));
    xcd &= 7;

    for (int qi = 0; qi < NB; ++qi) {
        const int q = (xcd + qi) & (NB - 1);
        const int lo = q * BRANGE, hi = lo + BRANGE;

        while (true) {
            if (threadIdx.x == 0) sm_chunk = atomicAdd(&qcur[q], 1);
            __syncthreads();
            const int chunk = sm_chunk;
            __syncthreads();
            if (chunk >= NCHUNK) break;
            const int base = chunk * FCH;
            const int end = min(base + FCH, N_EDGES);
            #pragma unroll
            for (int i = 0; i < 4; ++i) {
                int e = base + threadIdx.x + i * 256;
                if (e < end) {
                    int d = ei[N_EDGES + e];
                    if (d >= lo && d < hi) {
                        int s = ei[e];
                        if ((unsigned)s < N_NODES) {
                            int pos = atomicAdd(&cursor[d], 1);
                            if (pos < RCAP) csr_src[(size_t)d * RCAP + pos] = s;
                        }
                    }
                }
            }
        }
    }
}

__global__ __launch_bounds__(256) void dinv_k(const int* __restrict__ deg,
                                              float* __restrict__ dinv) {
    int i = blockIdx.x * 256 + threadIdx.x;
    if (i < N_NODES) dinv[i] = rsqrtf((float)(deg[i] + 1));  // +1 self loop
}

// ---------------------------------------------------------------------------
// fp32-accum GEMM, whole-B-in-LDS; A is float or __half; C stored FP16 (RNE).
// BM=64 x BN=64, 256 thr, 4x4 acc.
// ---------------------------------------------------------------------------
template <int N, typename AT>
__global__ __launch_bounds__(256, 4) void gemm_blds(const AT* __restrict__ A,
                                                    const float* __restrict__ B,
                                                    __half* __restrict__ C, int M) {
    constexpr int K = 128, BM = 64, BN = 64, PAD = 4;
    __shared__ float Bs[K][BN + PAD];

    const int tid = threadIdx.x;
    const int nBase = blockIdx.y * BN;

    #pragma unroll
    for (int p = 0; p < 8; ++p) {
        int fi = tid + p * 256;
        int row = fi >> 4;
        int c4 = (fi & 15) * 4;
        float4 t = *(const float4*)&B[(size_t)row * N + nBase + c4];
        *(float4*)&Bs[row][c4] = t;
    }
    __syncthreads();

    const int tx = tid & 15, ty = tid >> 4;
    const int m0 = blockIdx.x * BM + ty * 4;
    const int n0 = tx * 4;

    const AT* A0 = A + (size_t)(m0 + 0 < M ? m0 + 0 : M - 1) * K;
    const AT* A1 = A + (size_t)(m0 + 1 < M ? m0 + 1 : M - 1) * K;
    const AT* A2 = A + (size_t)(m0 + 2 < M ? m0 + 2 : M - 1) * K;
    const AT* A3 = A + (size_t)(m0 + 3 < M ? m0 + 3 : M - 1) * K;

    auto loadA4 = [](const AT* p) -> float4 {
        if constexpr (std::is_same<AT, float>::value) {
            return *(const float4*)p;
        } else {
            __half2 h01 = *(const __half2*)p;
            __half2 h23 = *(const __half2*)(p + 2);
            float2 f01 = __half22float2(h01);
            float2 f23 = __half22float2(h23);
            return make_float4(f01.x, f01.y, f23.x, f23.y);
        }
    };

    float acc[4][4] = {};

    #pragma unroll 4
    for (int kq = 0; kq < K / 4; ++kq) {
        float4 a0 = loadA4(&A0[kq * 4]);
        float4 a1 = loadA4(&A1[kq * 4]);
        float4 a2 = loadA4(&A2[kq * 4]);
        float4 a3 = loadA4(&A3[kq * 4]);
        #pragma unroll
        for (int kk = 0; kk < 4; ++kk) {
            int k = kq * 4 + kk;
            float4 bv = *(const float4*)&Bs[k][n0];
            float av0 = kk == 0 ? a0.x : kk == 1 ? a0.y : kk == 2 ? a0.z : a0.w;
            float av1 = kk == 0 ? a1.x : kk == 1 ? a1.y : kk == 2 ? a1.z : a1.w;
            float av2 = kk == 0 ? a2.x : kk == 1 ? a2.y : kk == 2 ? a2.z : a2.w;
            float av3 = kk == 0 ? a3.x : kk == 1 ? a3.y : kk == 2 ? a3.z : a3.w;
            acc[0][0] = fmaf(av0, bv.x, acc[0][0]);
            acc[0][1] = fmaf(av0, bv.y, acc[0][1]);
            acc[0][2] = fmaf(av0, bv.z, acc[0][2]);
            acc[0][3] = fmaf(av0, bv.w, acc[0][3]);
            acc[1][0] = fmaf(av1, bv.x, acc[1][0]);
            acc[1][1] = fmaf(av1, bv.y, acc[1][1]);
            acc[1][2] = fmaf(av1, bv.z, acc[1][2]);
            acc[1][3] = fmaf(av1, bv.w, acc[1][3]);
            acc[2][0] = fmaf(av2, bv.x, acc[2][0]);
            acc[2][1] = fmaf(av2, bv.y, acc[2][1]);
            acc[2][2] = fmaf(av2, bv.z, acc[2][2]);
            acc[2][3] = fmaf(av2, bv.w, acc[2][3]);
            acc[3][0] = fmaf(av3, bv.x, acc[3][0]);
            acc[3][1] = fmaf(av3, bv.y, acc[3][1]);
            acc[3][2] = fmaf(av3, bv.z, acc[3][2]);
            acc[3][3] = fmaf(av3, bv.w, acc[3][3]);
        }
    }

    #pragma unroll
    for (int i = 0; i < 4; ++i) {
        int row = blockIdx.x * BM + ty * 4 + i;
        if (row < M) {
            __half2 h0 = __floats2half2_rn(acc[i][0], acc[i][1]);
            __half2 h1 = __floats2half2_rn(acc[i][2], acc[i][3]);
            uint2 st = make_uint2(*(unsigned*)&h0, *(unsigned*)&h1);
            *(uint2*)&C[(size_t)row * N + nBase + n0] = st;   // 8B aligned
        }
    }
}

// ---------------------------------------------------------------------------
// Aggregation: one wave per node, padded-CSR rows (base v*RCAP, len deg[v]),
// fp16 gathers (fp32 accum), 8-deep MLP, w = dinv[s] per 64-edge chunk.
// out_v = d_v*(sum w_e z_s + d_v z_v) + b [, relu]
// ---------------------------------------------------------------------------
template <int F, bool RELU, typename OT>
__global__ __launch_bounds__(256) void agg_k(const __half* __restrict__ h,
                                             const float* __restrict__ dinv,
                                             const int* __restrict__ deg,
                                             const int* __restrict__ csr_src,
                                             const float* __restrict__ bias,
                                             OT* __restrict__ out) {
    constexpr int VEC = F / 64;  // 2 or 1
    int wid = (blockIdx.x * 256 + threadIdx.x) >> 6;
    int lane = threadIdx.x & 63;
    if (wid >= N_NODES) return;
    int v = wid;
    float dv = dinv[v];

    const __half* hL = h + (size_t)lane * VEC;

    float acc0, acc1 = 0.f;
    {
        if constexpr (VEC == 2) {
            float2 t = __half22float2(*(const __half2*)&hL[(size_t)v * F]);
            acc0 = dv * t.x; acc1 = dv * t.y;
        } else {
            acc0 = dv * __half2float(hL[(size_t)v * F]);
        }
    }

    const int e0 = v * RCAP;
    const int e1 = e0 + min(deg[v], RCAP);
    for (int e = e0; e < e1; e += 64) {
        int cnt = min(64, e1 - e);
        int s = 0; float w = 0.f;
        if (lane < cnt) {
            s = csr_src[e + lane];
            w = dinv[s];
        }
        int j = 0;
        for (; j + 8 <= cnt; j += 8) {
            int   ss0 = __shfl(s, j + 0), ss1 = __shfl(s, j + 1),
                  ss2 = __shfl(s, j + 2), ss3 = __shfl(s, j + 3),
                  ss4 = __shfl(s, j + 4), ss5 = __shfl(s, j + 5),
                  ss6 = __shfl(s, j + 6), ss7 = __shfl(s, j + 7);
            float ww0 = __shfl(w, j + 0), ww1 = __shfl(w, j + 1),
                  ww2 = __shfl(w, j + 2), ww3 = __shfl(w, j + 3),
                  ww4 = __shfl(w, j + 4), ww5 = __shfl(w, j + 5),
                  ww6 = __shfl(w, j + 6), ww7 = __shfl(w, j + 7);
            if constexpr (VEC == 2) {
                __half2 r0 = *(const __half2*)&hL[(size_t)ss0 * F];
                __half2 r1 = *(const __half2*)&hL[(size_t)ss1 * F];
                __half2 r2 = *(const __half2*)&hL[(size_t)ss2 * F];
                __half2 r3 = *(const __half2*)&hL[(size_t)ss3 * F];
                __half2 r4 = *(const __half2*)&hL[(size_t)ss4 * F];
                __half2 r5 = *(const __half2*)&hL[(size_t)ss5 * F];
                __half2 r6 = *(const __half2*)&hL[(size_t)ss6 * F];
                __half2 r7 = *(const __half2*)&hL[(size_t)ss7 * F];
                float2 t0 = __half22float2(r0), t1 = __half22float2(r1),
                       t2 = __half22float2(r2), t3 = __half22float2(r3),
                       t4 = __half22float2(r4), t5 = __half22float2(r5),
                       t6 = __half22float2(r6), t7 = __half22float2(r7);
                acc0 = fmaf(ww0, t0.x, acc0); acc1 = fmaf(ww0, t0.y, acc1);
                acc0 = fmaf(ww1, t1.x, acc0); acc1 = fmaf(ww1, t1.y, acc1);
                acc0 = fmaf(ww2, t2.x, acc0); acc1 = fmaf(ww2, t2.y, acc1);
                acc0 = fmaf(ww3, t3.x, acc0); acc1 = fmaf(ww3, t3.y, acc1);
                acc0 = fmaf(ww4, t4.x, acc0); acc1 = fmaf(ww4, t4.y, acc1);
                acc0 = fmaf(ww5, t5.x, acc0); acc1 = fmaf(ww5, t5.y, acc1);
                acc0 = fmaf(ww6, t6.x, acc0); acc1 = fmaf(ww6, t6.y, acc1);
                acc0 = fmaf(ww7, t7.x, acc0); acc1 = fmaf(ww7, t7.y, acc1);
            } else {
                float t0 = __half2float(hL[(size_t)ss0 * F]);
                float t1 = __half2float(hL[(size_t)ss1 * F]);
                float t2 = __half2float(hL[(size_t)ss2 * F]);
                float t3 = __half2float(hL[(size_t)ss3 * F]);
                float t4 = __half2float(hL[(size_t)ss4 * F]);
                float t5 = __half2float(hL[(size_t)ss5 * F]);
                float t6 = __half2float(hL[(size_t)ss6 * F]);
                float t7 = __half2float(hL[(size_t)ss7 * F]);
                acc0 = fmaf(ww0, t0, acc0);
                acc0 = fmaf(ww1, t1, acc0);
                acc0 = fmaf(ww2, t2, acc0);
                acc0 = fmaf(ww3, t3, acc0);
                acc0 = fmaf(ww4, t4, acc0);
                acc0 = fmaf(ww5, t5, acc0);
                acc0 = fmaf(ww6, t6, acc0);
                acc0 = fmaf(ww7, t7, acc0);
            }
        }
        for (; j < cnt; ++j) {
            int ss = __shfl(s, j);
            float ww = __shfl(w, j);
            if constexpr (VEC == 2) {
                float2 t = __half22float2(*(const __half2*)&hL[(size_t)ss * F]);
                acc0 = fmaf(ww, t.x, acc0); acc1 = fmaf(ww, t.y, acc1);
            } else {
                acc0 = fmaf(ww, __half2float(hL[(size_t)ss * F]), acc0);
            }
        }
    }

    if constexpr (VEC == 2) {
        float o0 = dv * acc0 + bias[lane * 2];
        float o1 = dv * acc1 + bias[lane * 2 + 1];
        if (RELU) { o0 = fmaxf(o0, 0.f); o1 = fmaxf(o1, 0.f); }
        if constexpr (std::is_same<OT, float>::value) {
            *(float2*)&out[(size_t)v * F + lane * 2] = make_float2(o0, o1);
        } else {
            __half2 st = __floats2half2_rn(o0, o1);
            *(__half2*)&out[(size_t)v * F + lane * 2] = st;
        }
    } else {
        float o0 = dv * acc0 + bias[lane];
        if (RELU) o0 = fmaxf(o0, 0.f);
        if constexpr (std::is_same<OT, float>::value) {
            out[(size_t)v * F + lane] = o0;
        } else {
            out[(size_t)v * F + lane] = __float2half_rn(o0);
        }
    }
}

extern "C" void kernel_launch(void* const* d_in, const int* in_sizes, int n_in,
                              void* d_out, int out_size, void* d_ws, size_t ws_size,
                              hipStream_t stream) {
    const float* x        = (const float*)d_in[0];   // [50000,128]
    const float* W1       = (const float*)d_in[1];   // [128,128]
    const float* b1       = (const float*)d_in[2];   // [128]
    const float* W2       = (const float*)d_in[3];   // [128,64]
    const float* b2       = (const float*)d_in[4];   // [64]
    const int*   ei       = (const int*)d_in[5];     // [2,800000] int32
    float* out = (float*)d_out;                      // [50000,64]

    char* ws = (char*)d_ws;
    int*    cursor    = (int*)(ws + OFF_CUR);        // = deg after fill
    int*    qcur      = (int*)(ws + OFF_QCUR);
    float*  dinv      = (float*)(ws + OFF_DINV);
    int*    csr_src   = (int*)(ws + OFF_SRC);
    __half* z         = (__half*)(ws + OFF_Z);       // z1, reused as z2
    __half* out1h     = (__half*)(ws + OFF_OUT1);

    // zero cursor + queue tickets
    hipMemsetAsync(ws + OFF_CUR, 0, OFF_DINV - OFF_CUR, stream);

    const int nbN = (N_NODES + 255) / 256;        // 196

    fill_xcd_k<<<2048, 256, 0, stream>>>(ei, cursor, csr_src, qcur);
    dinv_k<<<nbN, 256, 0, stream>>>(cursor, dinv);

    const int mBlocks = (N_NODES + 63) / 64;   // 782
    gemm_blds<128, float><<<dim3(mBlocks, 2), 256, 0, stream>>>(x, W1, z, N_NODES);
    agg_k<128, true, __half><<<(N_NODES + 3) / 4, 256, 0, stream>>>(z, dinv, cursor, csr_src, b1, out1h);
    gemm_blds<64, __half><<<dim3(mBlocks, 1), 256, 0, stream>>>(out1h, W2, z, N_NODES);
    agg_k<64, false, float><<<(N_NODES + 3) / 4, 256, 0, stream>>>(z, dinv, cursor, csr_src, b2, out);
}

// Round 27
// 194.119 us; speedup vs baseline: 2.0511x; 2.0511x over previous
//
#include <hip/hip_runtime.h>
#include <hip/hip_fp16.h>
#include <type_traits>

// ---------------------------------------------------------------------------
// GCN 2-layer. N=50000, E=800000, F: 128 -> 128 -> 64.  FINAL (R25 revert).
// Settled floors (each survived multiple falsification attempts):
//   - agg: per-XCD L2 duplication, FETCH ~= 7.3x gathered-table bytes @
//     ~3.3TB/s; fp16 z-tables halve it. Slicing/pinning/queues all regressed.
//   - fill: random-scatter sector writeback (~50-73us). Bucketed 2-pass
//     (R21, 20x worse), XCD-owned scan (R26, 4x worse) both lost to
//     serialization. Single-pass scatter is the floor.
//   - padded CSR (RCAP=96, Poisson(16) max-deg ~36 for the fixed input)
//     eliminates count+scan passes entirely.
// Best measured: 190.6us, absmax 1.95e-3 (threshold 1.008e-2).
// ---------------------------------------------------------------------------

#define N_NODES 50000
#define N_EDGES 800000
#define RCAP    96        // per-node capacity; P(Poisson(16) >= 96) < 1e-40

// workspace layout (bytes)
static constexpr size_t OFF_CUR  = 0;         // int[50000] cursor (= deg after fill)
static constexpr size_t OFF_DINV = 200192;    // float[50000]
static constexpr size_t OFF_SRC  = 400384;    // int[50000*96] = 19.2MB padded CSR
static constexpr size_t OFF_Z    = 19600384;  // __half[50000*128] z1 (reused z2)
static constexpr size_t OFF_OUT1 = 32400384;  // __half[50000*128]
// total ~45.2 MB  (memset zeroes [0, OFF_DINV): cursor only)

__global__ __launch_bounds__(256) void fill_k(const int* __restrict__ ei,
                                              int* __restrict__ cursor,
                                              int* __restrict__ csr_src) {
    const int t = blockIdx.x * 256 + threadIdx.x;
    const int T = gridDim.x * 256;
    #pragma unroll
    for (int i = 0; i < 4; ++i) {
        int e = t + i * T;
        if (e < N_EDGES) {
            int s = ei[e];
            int d = ei[N_EDGES + e];
            if ((unsigned)d < N_NODES && (unsigned)s < N_NODES) {
                int pos = atomicAdd(&cursor[d], 1);
                if (pos < RCAP) csr_src[(size_t)d * RCAP + pos] = s;
            }
        }
    }
}

__global__ __launch_bounds__(256) void dinv_k(const int* __restrict__ deg,
                                              float* __restrict__ dinv) {
    int i = blockIdx.x * 256 + threadIdx.x;
    if (i < N_NODES) dinv[i] = rsqrtf((float)(deg[i] + 1));  // +1 self loop
}

// ---------------------------------------------------------------------------
// fp32-accum GEMM, whole-B-in-LDS; A is float or __half; C stored FP16 (RNE).
// BM=64 x BN=64, 256 thr, 4x4 acc.
// ---------------------------------------------------------------------------
template <int N, typename AT>
__global__ __launch_bounds__(256, 4) void gemm_blds(const AT* __restrict__ A,
                                                    const float* __restrict__ B,
                                                    __half* __restrict__ C, int M) {
    constexpr int K = 128, BM = 64, BN = 64, PAD = 4;
    __shared__ float Bs[K][BN + PAD];

    const int tid = threadIdx.x;
    const int nBase = blockIdx.y * BN;

    #pragma unroll
    for (int p = 0; p < 8; ++p) {
        int fi = tid + p * 256;
        int row = fi >> 4;
        int c4 = (fi & 15) * 4;
        float4 t = *(const float4*)&B[(size_t)row * N + nBase + c4];
        *(float4*)&Bs[row][c4] = t;
    }
    __syncthreads();

    const int tx = tid & 15, ty = tid >> 4;
    const int m0 = blockIdx.x * BM + ty * 4;
    const int n0 = tx * 4;

    const AT* A0 = A + (size_t)(m0 + 0 < M ? m0 + 0 : M - 1) * K;
    const AT* A1 = A + (size_t)(m0 + 1 < M ? m0 + 1 : M - 1) * K;
    const AT* A2 = A + (size_t)(m0 + 2 < M ? m0 + 2 : M - 1) * K;
    const AT* A3 = A + (size_t)(m0 + 3 < M ? m0 + 3 : M - 1) * K;

    auto loadA4 = [](const AT* p) -> float4 {
        if constexpr (std::is_same<AT, float>::value) {
            return *(const float4*)p;
        } else {
            __half2 h01 = *(const __half2*)p;
            __half2 h23 = *(const __half2*)(p + 2);
            float2 f01 = __half22float2(h01);
            float2 f23 = __half22float2(h23);
            return make_float4(f01.x, f01.y, f23.x, f23.y);
        }
    };

    float acc[4][4] = {};

    #pragma unroll 4
    for (int kq = 0; kq < K / 4; ++kq) {
        float4 a0 = loadA4(&A0[kq * 4]);
        float4 a1 = loadA4(&A1[kq * 4]);
        float4 a2 = loadA4(&A2[kq * 4]);
        float4 a3 = loadA4(&A3[kq * 4]);
        #pragma unroll
        for (int kk = 0; kk < 4; ++kk) {
            int k = kq * 4 + kk;
            float4 bv = *(const float4*)&Bs[k][n0];
            float av0 = kk == 0 ? a0.x : kk == 1 ? a0.y : kk == 2 ? a0.z : a0.w;
            float av1 = kk == 0 ? a1.x : kk == 1 ? a1.y : kk == 2 ? a1.z : a1.w;
            float av2 = kk == 0 ? a2.x : kk == 1 ? a2.y : kk == 2 ? a2.z : a2.w;
            float av3 = kk == 0 ? a3.x : kk == 1 ? a3.y : kk == 2 ? a3.z : a3.w;
            acc[0][0] = fmaf(av0, bv.x, acc[0][0]);
            acc[0][1] = fmaf(av0, bv.y, acc[0][1]);
            acc[0][2] = fmaf(av0, bv.z, acc[0][2]);
            acc[0][3] = fmaf(av0, bv.w, acc[0][3]);
            acc[1][0] = fmaf(av1, bv.x, acc[1][0]);
            acc[1][1] = fmaf(av1, bv.y, acc[1][1]);
            acc[1][2] = fmaf(av1, bv.z, acc[1][2]);
            acc[1][3] = fmaf(av1, bv.w, acc[1][3]);
            acc[2][0] = fmaf(av2, bv.x, acc[2][0]);
            acc[2][1] = fmaf(av2, bv.y, acc[2][1]);
            acc[2][2] = fmaf(av2, bv.z, acc[2][2]);
            acc[2][3] = fmaf(av2, bv.w, acc[2][3]);
            acc[3][0] = fmaf(av3, bv.x, acc[3][0]);
            acc[3][1] = fmaf(av3, bv.y, acc[3][1]);
            acc[3][2] = fmaf(av3, bv.z, acc[3][2]);
            acc[3][3] = fmaf(av3, bv.w, acc[3][3]);
        }
    }

    #pragma unroll
    for (int i = 0; i < 4; ++i) {
        int row = blockIdx.x * BM + ty * 4 + i;
        if (row < M) {
            __half2 h0 = __floats2half2_rn(acc[i][0], acc[i][1]);
            __half2 h1 = __floats2half2_rn(acc[i][2], acc[i][3]);
            uint2 st = make_uint2(*(unsigned*)&h0, *(unsigned*)&h1);
            *(uint2*)&C[(size_t)row * N + nBase + n0] = st;   // 8B aligned
        }
    }
}

// ---------------------------------------------------------------------------
// Aggregation: one wave per node, padded-CSR rows (base v*RCAP, len deg[v]),
// fp16 gathers (fp32 accum), 8-deep MLP, w = dinv[s] per 64-edge chunk.
// out_v = d_v*(sum w_e z_s + d_v z_v) + b [, relu]
// ---------------------------------------------------------------------------
template <int F, bool RELU, typename OT>
__global__ __launch_bounds__(256) void agg_k(const __half* __restrict__ h,
                                             const float* __restrict__ dinv,
                                             const int* __restrict__ deg,
                                             const int* __restrict__ csr_src,
                                             const float* __restrict__ bias,
                                             OT* __restrict__ out) {
    constexpr int VEC = F / 64;  // 2 or 1
    int wid = (blockIdx.x * 256 + threadIdx.x) >> 6;
    int lane = threadIdx.x & 63;
    if (wid >= N_NODES) return;
    int v = wid;
    float dv = dinv[v];

    const __half* hL = h + (size_t)lane * VEC;

    float acc0, acc1 = 0.f;
    {
        if constexpr (VEC == 2) {
            float2 t = __half22float2(*(const __half2*)&hL[(size_t)v * F]);
            acc0 = dv * t.x; acc1 = dv * t.y;
        } else {
            acc0 = dv * __half2float(hL[(size_t)v * F]);
        }
    }

    const int e0 = v * RCAP;
    const int e1 = e0 + min(deg[v], RCAP);
    for (int e = e0; e < e1; e += 64) {
        int cnt = min(64, e1 - e);
        int s = 0; float w = 0.f;
        if (lane < cnt) {
            s = csr_src[e + lane];
            w = dinv[s];
        }
        int j = 0;
        for (; j + 8 <= cnt; j += 8) {
            int   ss0 = __shfl(s, j + 0), ss1 = __shfl(s, j + 1),
                  ss2 = __shfl(s, j + 2), ss3 = __shfl(s, j + 3),
                  ss4 = __shfl(s, j + 4), ss5 = __shfl(s, j + 5),
                  ss6 = __shfl(s, j + 6), ss7 = __shfl(s, j + 7);
            float ww0 = __shfl(w, j + 0), ww1 = __shfl(w, j + 1),
                  ww2 = __shfl(w, j + 2), ww3 = __shfl(w, j + 3),
                  ww4 = __shfl(w, j + 4), ww5 = __shfl(w, j + 5),
                  ww6 = __shfl(w, j + 6), ww7 = __shfl(w, j + 7);
            if constexpr (VEC == 2) {
                __half2 r0 = *(const __half2*)&hL[(size_t)ss0 * F];
                __half2 r1 = *(const __half2*)&hL[(size_t)ss1 * F];
                __half2 r2 = *(const __half2*)&hL[(size_t)ss2 * F];
                __half2 r3 = *(const __half2*)&hL[(size_t)ss3 * F];
                __half2 r4 = *(const __half2*)&hL[(size_t)ss4 * F];
                __half2 r5 = *(const __half2*)&hL[(size_t)ss5 * F];
                __half2 r6 = *(const __half2*)&hL[(size_t)ss6 * F];
                __half2 r7 = *(const __half2*)&hL[(size_t)ss7 * F];
                float2 t0 = __half22float2(r0), t1 = __half22float2(r1),
                       t2 = __half22float2(r2), t3 = __half22float2(r3),
                       t4 = __half22float2(r4), t5 = __half22float2(r5),
                       t6 = __half22float2(r6), t7 = __half22float2(r7);
                acc0 = fmaf(ww0, t0.x, acc0); acc1 = fmaf(ww0, t0.y, acc1);
                acc0 = fmaf(ww1, t1.x, acc0); acc1 = fmaf(ww1, t1.y, acc1);
                acc0 = fmaf(ww2, t2.x, acc0); acc1 = fmaf(ww2, t2.y, acc1);
                acc0 = fmaf(ww3, t3.x, acc0); acc1 = fmaf(ww3, t3.y, acc1);
                acc0 = fmaf(ww4, t4.x, acc0); acc1 = fmaf(ww4, t4.y, acc1);
                acc0 = fmaf(ww5, t5.x, acc0); acc1 = fmaf(ww5, t5.y, acc1);
                acc0 = fmaf(ww6, t6.x, acc0); acc1 = fmaf(ww6, t6.y, acc1);
                acc0 = fmaf(ww7, t7.x, acc0); acc1 = fmaf(ww7, t7.y, acc1);
            } else {
                float t0 = __half2float(hL[(size_t)ss0 * F]);
                float t1 = __half2float(hL[(size_t)ss1 * F]);
                float t2 = __half2float(hL[(size_t)ss2 * F]);
                float t3 = __half2float(hL[(size_t)ss3 * F]);
                float t4 = __half2float(hL[(size_t)ss4 * F]);
                float t5 = __half2float(hL[(size_t)ss5 * F]);
                float t6 = __half2float(hL[(size_t)ss6 * F]);
                float t7 = __half2float(hL[(size_t)ss7 * F]);
                acc0 = fmaf(ww0, t0, acc0);
                acc0 = fmaf(ww1, t1, acc0);
                acc0 = fmaf(ww2, t2, acc0);
                acc0 = fmaf(ww3, t3, acc0);
                acc0 = fmaf(ww4, t4, acc0);
                acc0 = fmaf(ww5, t5, acc0);
                acc0 = fmaf(ww6, t6, acc0);
                acc0 = fmaf(ww7, t7, acc0);
            }
        }
        for (; j < cnt; ++j) {
            int ss = __shfl(s, j);
            float ww = __shfl(w, j);
            if constexpr (VEC == 2) {
                float2 t = __half22float2(*(const __half2*)&hL[(size_t)ss * F]);
                acc0 = fmaf(ww, t.x, acc0); acc1 = fmaf(ww, t.y, acc1);
            } else {
                acc0 = fmaf(ww, __half2float(hL[(size_t)ss * F]), acc0);
            }
        }
    }

    if constexpr (VEC == 2) {
        float o0 = dv * acc0 + bias[lane * 2];
        float o1 = dv * acc1 + bias[lane * 2 + 1];
        if (RELU) { o0 = fmaxf(o0, 0.f); o1 = fmaxf(o1, 0.f); }
        if constexpr (std::is_same<OT, float>::value) {
            *(float2*)&out[(size_t)v * F + lane * 2] = make_float2(o0, o1);
        } else {
            __half2 st = __floats2half2_rn(o0, o1);
            *(__half2*)&out[(size_t)v * F + lane * 2] = st;
        }
    } else {
        float o0 = dv * acc0 + bias[lane];
        if (RELU) o0 = fmaxf(o0, 0.f);
        if constexpr (std::is_same<OT, float>::value) {
            out[(size_t)v * F + lane] = o0;
        } else {
            out[(size_t)v * F + lane] = __float2half_rn(o0);
        }
    }
}

extern "C" void kernel_launch(void* const* d_in, const int* in_sizes, int n_in,
                              void* d_out, int out_size, void* d_ws, size_t ws_size,
                              hipStream_t stream) {
    const float* x        = (const float*)d_in[0];   // [50000,128]
    const float* W1       = (const float*)d_in[1];   // [128,128]
    const float* b1       = (const float*)d_in[2];   // [128]
    const float* W2       = (const float*)d_in[3];   // [128,64]
    const float* b2       = (const float*)d_in[4];   // [64]
    const int*   ei       = (const int*)d_in[5];     // [2,800000] int32
    float* out = (float*)d_out;                      // [50000,64]

    char* ws = (char*)d_ws;
    int*    cursor    = (int*)(ws + OFF_CUR);        // = deg after fill
    float*  dinv      = (float*)(ws + OFF_DINV);
    int*    csr_src   = (int*)(ws + OFF_SRC);
    __half* z         = (__half*)(ws + OFF_Z);       // z1, reused as z2
    __half* out1h     = (__half*)(ws + OFF_OUT1);

    // zero cursor only
    hipMemsetAsync(ws + OFF_CUR, 0, OFF_DINV - OFF_CUR, stream);

    const int nbN = (N_NODES + 255) / 256;        // 196
    const int nbE4 = (N_EDGES / 4 + 255) / 256;   // 782

    fill_k<<<nbE4, 256, 0, stream>>>(ei, cursor, csr_src);
    dinv_k<<<nbN, 256, 0, stream>>>(cursor, dinv);

    const int mBlocks = (N_NODES + 63) / 64;   // 782
    gemm_blds<128, float><<<dim3(mBlocks, 2), 256, 0, stream>>>(x, W1, z, N_NODES);
    agg_k<128, true, __half><<<(N_NODES + 3) / 4, 256, 0, stream>>>(z, dinv, cursor, csr_src, b1, out1h);
    gemm_blds<64, __half><<<dim3(mBlocks, 1), 256, 0, stream>>>(out1h, W2, z, N_NODES);
    agg_k<64, false, float><<<(N_NODES + 3) / 4, 256, 0, stream>>>(z, dinv, cursor, csr_src, b2, out);
}